// Round 2
// baseline (2240.254 us; speedup 1.0000x reference)
//
#include <hip/hip_runtime.h>

typedef unsigned short u16;
typedef unsigned int u32;
typedef __attribute__((ext_vector_type(8))) short bf16x8;
typedef __attribute__((ext_vector_type(4))) float f32x4;

#define HH 16
#define NN 4096
#define DD 64
#define MM 256

constexpr float NORMALIZER = 0.35355339059327373f; // 64^-0.25
constexpr float HALF_NORM2 = 0.0625f;              // 0.5 * 64^-0.5
constexpr float RATIO      = 0.0625f;              // 256^-0.5
constexpr float EPSF       = 1e-4f;

__device__ inline float bf2f(u16 u) { return __uint_as_float(((u32)u) << 16); }
__device__ inline u16 f2bf(float f) {
    u32 b = __float_as_uint(f);
    u32 r = b + 0x7FFFu + ((b >> 16) & 1u);
    return (u16)(r >> 16);
}
__device__ inline float ldx(const void* p, size_t i, int mode) {
    return mode ? ((const float*)p)[i] : bf2f(((const u16*)p)[i]);
}
__device__ inline u32 encf(float f) {
    u32 b = __float_as_uint(f);
    return (b & 0x80000000u) ? ~b : (b | 0x80000000u);
}
__device__ inline float decf(u32 u) {
    return (u & 0x80000000u) ? __uint_as_float(u ^ 0x80000000u) : __uint_as_float(~u);
}

// ---------------- K0: input dtype detection ----------------
__global__ __launch_bounds__(256) void detect_kernel(const u32* __restrict__ q,
                                                     int* __restrict__ mode) {
    __shared__ int cnt;
    if (threadIdx.x == 0) cnt = 0;
    __syncthreads();
    int c = 0;
    for (int i = threadIdx.x; i < 4096; i += 256) {
        u32 w = q[i];
        u32 e = (w >> 23) & 0xffu;
        if ((e >= 103u && e <= 134u) || (w & 0x7fffffffu) == 0u) c++;
    }
    atomicAdd(&cnt, c);
    __syncthreads();
    if (threadIdx.x == 0) *mode = (cnt > 3072) ? 1 : 0;
}

// ---------------- K1: global max of key logits ----------------
__global__ __launch_bounds__(256) void kmax_kernel(const void* __restrict__ k,
                                                   const void* __restrict__ proj,
                                                   const int* __restrict__ mode_p,
                                                   u32* __restrict__ gmax_enc) {
    int mode = *mode_p;
    int h = blockIdx.x >> 8;
    int n0 = (blockIdx.x & 255) * 16;
    int tid = threadIdx.x;
    __shared__ float rows[16 * 64];
    __shared__ float wmax[4];
    float pr[64];
#pragma unroll
    for (int d = 0; d < 64; ++d) pr[d] = ldx(proj, (size_t)tid * 64 + d, mode);
    size_t kbase = (size_t)(h * NN + n0) * 64;
#pragma unroll
    for (int i = 0; i < 4; ++i) {
        int idx = i * 256 + tid;
        rows[idx] = ldx(k, kbase + idx, mode);
    }
    __syncthreads();
    float lmax = -1e30f;
    for (int r = 0; r < 16; ++r) {
        float s = 0.f;
#pragma unroll
        for (int d = 0; d < 64; ++d) s += rows[r * 64 + d] * pr[d];
        s *= NORMALIZER;
        lmax = fmaxf(lmax, s);
    }
    for (int off = 32; off; off >>= 1) lmax = fmaxf(lmax, __shfl_down(lmax, off));
    if ((tid & 63) == 0) wmax[tid >> 6] = lmax;
    __syncthreads();
    if (tid == 0) {
        float m = fmaxf(fmaxf(wmax[0], wmax[1]), fmaxf(wmax[2], wmax[3]));
        atomicMax(gmax_enc, encf(m));
    }
}

// ---------------- K2: key features kp + column sums ----------------
__global__ __launch_bounds__(256) void kp_kernel(const void* __restrict__ k,
                                                 const void* __restrict__ proj,
                                                 const int* __restrict__ mode_p,
                                                 const u32* __restrict__ gmax_enc,
                                                 u16* __restrict__ kp,
                                                 float* __restrict__ ksum) {
    int mode = *mode_p;
    int h = blockIdx.x >> 8;
    int n0 = (blockIdx.x & 255) * 16;
    int tid = threadIdx.x;
    __shared__ float rows[16 * 64];
    __shared__ float diag[16];
    float pr[64];
#pragma unroll
    for (int d = 0; d < 64; ++d) pr[d] = ldx(proj, (size_t)tid * 64 + d, mode);
    size_t kbase = (size_t)(h * NN + n0) * 64;
#pragma unroll
    for (int i = 0; i < 4; ++i) {
        int idx = i * 256 + tid;
        rows[idx] = ldx(k, kbase + idx, mode);
    }
    __syncthreads();
    if (tid < 16) {
        float s = 0.f;
#pragma unroll
        for (int d = 0; d < 64; ++d) { float x = rows[tid * 64 + d]; s += x * x; }
        diag[tid] = s * HALF_NORM2;
    }
    __syncthreads();
    float gmax = decf(*gmax_enc);
    float local = 0.f;
    for (int r = 0; r < 16; ++r) {
        float s = 0.f;
#pragma unroll
        for (int d = 0; d < 64; ++d) s += rows[r * 64 + d] * pr[d];
        s *= NORMALIZER;
        float val = RATIO * (__expf(s - diag[r] - gmax) + EPSF);
        kp[(size_t)(h * NN + n0 + r) * MM + tid] = f2bf(val);
        local += val;
    }
    atomicAdd(&ksum[h * MM + tid], local);
}

// ---------------- K3: query features qp (per-row max) ----------------
__global__ __launch_bounds__(256) void qp_kernel(const void* __restrict__ q,
                                                 const void* __restrict__ proj,
                                                 const int* __restrict__ mode_p,
                                                 u16* __restrict__ qp) {
    int mode = *mode_p;
    int h = blockIdx.x >> 8;
    int n0 = (blockIdx.x & 255) * 16;
    int tid = threadIdx.x;
    __shared__ float rows[16 * 64];
    __shared__ float diag[16];
    __shared__ float dashs[16 * 256];
    __shared__ float part[16 * 16];
    __shared__ float rmax[16];
    float pr[64];
#pragma unroll
    for (int d = 0; d < 64; ++d) pr[d] = ldx(proj, (size_t)tid * 64 + d, mode);
    size_t qbase = (size_t)(h * NN + n0) * 64;
#pragma unroll
    for (int i = 0; i < 4; ++i) {
        int idx = i * 256 + tid;
        rows[idx] = ldx(q, qbase + idx, mode);
    }
    __syncthreads();
    if (tid < 16) {
        float s = 0.f;
#pragma unroll
        for (int d = 0; d < 64; ++d) { float x = rows[tid * 64 + d]; s += x * x; }
        diag[tid] = s * HALF_NORM2;
    }
    __syncthreads();
    float dash[16];
    for (int r = 0; r < 16; ++r) {
        float s = 0.f;
#pragma unroll
        for (int d = 0; d < 64; ++d) s += rows[r * 64 + d] * pr[d];
        dash[r] = s * NORMALIZER;
        dashs[r * 256 + tid] = dash[r];
    }
    __syncthreads();
    {
        int r = tid & 15, c = tid >> 4;
        float pm = -1e30f;
#pragma unroll
        for (int j = 0; j < 16; ++j) pm = fmaxf(pm, dashs[r * 256 + c * 16 + j]);
        part[r * 16 + c] = pm;
    }
    __syncthreads();
    if (tid < 16) {
        float m = -1e30f;
#pragma unroll
        for (int c = 0; c < 16; ++c) m = fmaxf(m, part[tid * 16 + c]);
        rmax[tid] = m;
    }
    __syncthreads();
    for (int r = 0; r < 16; ++r) {
        float val = RATIO * (__expf(dash[r] - diag[r] - rmax[r]) + EPSF);
        qp[(size_t)(h * NN + n0 + r) * MM + tid] = f2bf(val);
    }
}

// ---------------- K4: context[h,m,e] = sum_n kp[n,m] * v[n,e] ----------------
__global__ __launch_bounds__(256) void ctx_kernel(const u16* __restrict__ kp,
                                                  const void* __restrict__ v,
                                                  const int* __restrict__ mode_p,
                                                  float* __restrict__ ctx) {
    int mode = *mode_p;
    int h = blockIdx.x;
    int m0 = blockIdx.y * 64;
    int nb = blockIdx.z * 512;
    int tid = threadIdx.x;
    int tm = tid >> 4, te = tid & 15;
    __shared__ float kpl[64 * 64];
    __shared__ float vl[64 * 64];
    float acc[4][4];
#pragma unroll
    for (int i = 0; i < 4; ++i)
#pragma unroll
        for (int j = 0; j < 4; ++j) acc[i][j] = 0.f;
    for (int chunk = 0; chunk < 8; ++chunk) {
        int nbase = nb + chunk * 64;
#pragma unroll
        for (int i = 0; i < 8; ++i) {
            int idx = i * 256 + tid;
            int nn = idx >> 5, c2 = idx & 31;
            u32 u = ((const u32*)(kp + (size_t)(h * NN + nbase + nn) * MM + m0))[c2];
            kpl[nn * 64 + 2 * c2] = bf2f((u16)(u & 0xffffu));
            kpl[nn * 64 + 2 * c2 + 1] = bf2f((u16)(u >> 16));
        }
#pragma unroll
        for (int i = 0; i < 16; ++i) {
            int idx = i * 256 + tid;
            int nn = idx >> 6, e = idx & 63;
            vl[idx] = ldx(v, (size_t)(h * NN + nbase + nn) * DD + e, mode);
        }
        __syncthreads();
        for (int nn = 0; nn < 64; ++nn) {
            float a[4], b[4];
#pragma unroll
            for (int i = 0; i < 4; ++i) a[i] = kpl[nn * 64 + tm + 16 * i];
#pragma unroll
            for (int j = 0; j < 4; ++j) b[j] = vl[nn * 64 + te + 16 * j];
#pragma unroll
            for (int i = 0; i < 4; ++i)
#pragma unroll
                for (int j = 0; j < 4; ++j) acc[i][j] += a[i] * b[j];
        }
        __syncthreads();
    }
#pragma unroll
    for (int i = 0; i < 4; ++i)
#pragma unroll
        for (int j = 0; j < 4; ++j)
            atomicAdd(&ctx[(size_t)(h * MM + m0 + tm + 16 * i) * DD + te + 16 * j], acc[i][j]);
}

// ---------------- K5: d_inv ----------------
__global__ __launch_bounds__(256) void dinv_kernel(const u16* __restrict__ qp,
                                                   const float* __restrict__ ksum,
                                                   float* __restrict__ dinv) {
    int gw = (int)((blockIdx.x * 256 + threadIdx.x) >> 6);
    int lane = threadIdx.x & 63;
    int h = gw >> 12;
    int n = gw & 4095;
    const u16* row = qp + (size_t)(h * NN + n) * MM;
    const float* ks = ksum + h * MM;
    float s = 0.f;
#pragma unroll
    for (int j = 0; j < 4; ++j) {
        int m = lane + 64 * j;
        s += bf2f(row[m]) * ks[m];
    }
    for (int off = 32; off; off >>= 1) s += __shfl_down(s, off);
    if (lane == 0) dinv[gw] = 1.0f / s;
}

// ---------------- K6: alignment out ----------------
__global__ __launch_bounds__(256) void out_kernel(const u16* __restrict__ qp,
                                                  const float* __restrict__ ctx,
                                                  const float* __restrict__ dinv,
                                                  const int* __restrict__ mode_p,
                                                  void* __restrict__ outv) {
    int mode = *mode_p;
    int h = blockIdx.x >> 6;
    int n0 = (blockIdx.x & 63) * 64;
    int tid = threadIdx.x;
    int w = tid >> 6, lane = tid & 63;
    __shared__ float ctxl[64 * 64];
    __shared__ u16 qpl[64 * 64];
    float acc[16];
#pragma unroll
    for (int j = 0; j < 16; ++j) acc[j] = 0.f;
    for (int mc = 0; mc < 4; ++mc) {
        int m0 = mc * 64;
#pragma unroll
        for (int i = 0; i < 16; ++i) {
            int idx = i * 256 + tid;
            int a = idx >> 6, b = idx & 63;
            ctxl[idx] = ctx[(size_t)(h * MM + m0 + a) * DD + b];
            qpl[idx] = qp[(size_t)(h * NN + n0 + a) * MM + m0 + b];
        }
        __syncthreads();
        for (int j = 0; j < 16; ++j) {
            int r = w * 16 + j;
            float s = acc[j];
            for (int m = 0; m < 64; ++m) s += bf2f(qpl[r * 64 + m]) * ctxl[m * 64 + lane];
            acc[j] = s;
        }
        __syncthreads();
    }
#pragma unroll
    for (int j = 0; j < 16; ++j) {
        int r = w * 16 + j;
        int n = n0 + r;
        float val = acc[j] * dinv[h * NN + n];
        size_t o = (size_t)(h * NN + n) * DD + lane;
        if (mode) ((float*)outv)[o] = val;
        else ((u16*)outv)[o] = f2bf(val);
    }
}

// ---------------- K7: weights = qp @ kp^T per head (MFMA) ----------------
__global__ __launch_bounds__(256) void weights_kernel(const u16* __restrict__ qp,
                                                      const u16* __restrict__ kp,
                                                      const int* __restrict__ mode_p,
                                                      void* __restrict__ woutv) {
    int mode = *mode_p;
    int bid = blockIdx.x;
    int h = bid >> 10;
    int t = bid & 1023;
    int qt = t >> 5, kt = t & 31;
    int tid = threadIdx.x;
    int w = tid >> 6, lane = tid & 63;
    int wq = w >> 1, wk = w & 1;
    int r = lane & 15, quad = lane >> 4;
    const u16* qh = qp + (size_t)h * NN * MM;
    const u16* kh = kp + (size_t)h * NN * MM;
    int qrow0 = qt * 128 + wq * 64;
    int krow0 = kt * 128 + wk * 64;
    f32x4 acc[4][4];
#pragma unroll
    for (int i = 0; i < 4; ++i)
#pragma unroll
        for (int j = 0; j < 4; ++j)
#pragma unroll
            for (int e = 0; e < 4; ++e) acc[i][j][e] = 0.f;
    for (int k0 = 0; k0 < 256; k0 += 32) {
        bf16x8 af[4], bfr[4];
#pragma unroll
        for (int i = 0; i < 4; ++i)
            af[i] = *(const bf16x8*)(qh + (size_t)(qrow0 + i * 16 + r) * MM + k0 + quad * 8);
#pragma unroll
        for (int j = 0; j < 4; ++j)
            bfr[j] = *(const bf16x8*)(kh + (size_t)(krow0 + j * 16 + r) * MM + k0 + quad * 8);
#pragma unroll
        for (int i = 0; i < 4; ++i)
#pragma unroll
            for (int j = 0; j < 4; ++j)
                acc[i][j] = __builtin_amdgcn_mfma_f32_16x16x32_bf16(af[i], bfr[j], acc[i][j], 0, 0, 0);
    }
    // weights start at element offset H*N*D = 4194304 within d_out
    size_t wbase = 4194304 + (size_t)h * NN * NN;
    if (mode) {
        float* wout = (float*)woutv;
#pragma unroll
        for (int i = 0; i < 4; ++i)
#pragma unroll
            for (int j = 0; j < 4; ++j)
#pragma unroll
                for (int e = 0; e < 4; ++e) {
                    int qr = qrow0 + i * 16 + quad * 4 + e;
                    int kc = krow0 + j * 16 + r;
                    wout[wbase + (size_t)qr * NN + kc] = acc[i][j][e];
                }
    } else {
        u16* wout = (u16*)woutv;
#pragma unroll
        for (int i = 0; i < 4; ++i)
#pragma unroll
            for (int j = 0; j < 4; ++j)
#pragma unroll
                for (int e = 0; e < 4; ++e) {
                    int qr = qrow0 + i * 16 + quad * 4 + e;
                    int kc = krow0 + j * 16 + r;
                    wout[wbase + (size_t)qr * NN + kc] = f2bf(acc[i][j][e]);
                }
    }
}

extern "C" void kernel_launch(void* const* d_in, const int* in_sizes, int n_in,
                              void* d_out, int out_size, void* d_ws, size_t ws_size,
                              hipStream_t stream) {
    (void)in_sizes; (void)n_in; (void)out_size; (void)ws_size;
    const void* q = d_in[0];
    const void* k = d_in[1];
    const void* v = d_in[2];
    const void* proj = d_in[3];

    char* ws = (char*)d_ws;
    u16* kp = (u16*)ws;                                    // 32 MB
    u16* qp = (u16*)(ws + 33554432);                       // 32 MB
    float* ksum = (float*)(ws + 67108864);                 // 16 KB
    float* ctx = (float*)(ws + 67125248);                  // 1 MB
    u32* gmax = (u32*)(ws + 68173824);                     // 4 B (padded)
    float* dinv = (float*)(ws + 68174080);                 // 256 KB
    int* mode = (int*)(ws + 68436224);                     // 4 B

    hipMemsetAsync(ws + 67108864, 0, 1065216, stream);

    detect_kernel<<<1, 256, 0, stream>>>((const u32*)q, mode);
    kmax_kernel<<<4096, 256, 0, stream>>>(k, proj, mode, gmax);
    kp_kernel<<<4096, 256, 0, stream>>>(k, proj, mode, gmax, kp, ksum);
    qp_kernel<<<4096, 256, 0, stream>>>(q, proj, mode, qp);
    ctx_kernel<<<dim3(16, 4, 8), 256, 0, stream>>>(kp, v, mode, ctx);
    dinv_kernel<<<16384, 256, 0, stream>>>(qp, ksum, dinv);
    out_kernel<<<1024, 256, 0, stream>>>(qp, ctx, dinv, mode, d_out);
    weights_kernel<<<16384, 256, 0, stream>>>(qp, kp, mode, d_out);
}